// Round 9
// baseline (198.713 us; speedup 1.0000x reference)
//
#include <hip/hip_runtime.h>
#include <math.h>

#define NB   64
#define T0   1024
#define CIN  128
#define HID  256
#define TGT  128
#define PRED 192
#define NROWS (NB*CIN)
#define KTOT 1792   // 1024+512+256

typedef __attribute__((ext_vector_type(4))) float f32x4;
typedef __attribute__((ext_vector_type(8))) short s16x8;

// ---------------- workspace layout (float offsets) ----------------
static const size_t XCT_OFF    = 0;          // [64][128][1024] f32
static const size_t S1_OFF     = 8388608;    // [64][128][512]
static const size_t S2_OFF     = 12582912;   // [64][128][256]
static const size_t P0_OFF     = 14680064;   // fft partials [1024][520+264+136]
static const size_t PARTS2_OFF = 15622144;   // [3][16][520]
static const size_t META_OFF   = 15647104;   // freqs int[9]@0, wk f32[9]@16, sw f32[3]@32
static const size_t W2T_OFF    = 15647168;   // [128 o][128 c-swizzled] bf16
static const size_t PBS_OFF    = 15655360;   // Pb[128], S_ch[128]
static const size_t WSUM_OFF   = 15655616;   // [3][192] (sw-prescaled)
static const size_t TB32_OFF   = 15656192;   // u32 [3][1024] base pairs
static const size_t TB16_OFF   = 15659264;   // u16 [3][1024] base k2
static const size_t WTB_OFF    = 15660800;   // bf16 [192][1792] sw-prescaled
static const size_t DWM_OFF    = 15832832;   // bf16 [8192][1792]
static const size_t TP_OFF     = 23172864;   // bf16 [192][8192]
// end = 23959296 floats = 95.8 MB

__device__ inline unsigned short f2bf(float x) {
    union { float f; unsigned u; } v; v.f = x;
    unsigned r = (v.u + 0x7FFFu + ((v.u >> 16) & 1u)) >> 16;
    return (unsigned short)r;
}
__device__ inline float bf2f(unsigned short u) {
    union { unsigned u; float f; } v; v.u = ((unsigned)u) << 16;
    return v.f;
}

// ---------------- fused: transpose x[B,T,C]->xct[B,C,T] + pool1 + pool2 ----------------
__global__ __launch_bounds__(256) void front(const float* __restrict__ x,
        float* __restrict__ xct, float* __restrict__ s1, float* __restrict__ s2) {
    __shared__ float tile[32][33];
    int b = blockIdx.z;
    int t0 = blockIdx.x * 32, c0 = blockIdx.y * 32;
    int tx = threadIdx.x, ty = threadIdx.y;       // 32 x 8
#pragma unroll
    for (int i = 0; i < 4; i++) {
        int t = t0 + ty + i * 8, c = c0 + tx;
        tile[ty + i * 8][tx] = x[((size_t)b * T0 + t) * CIN + c];
    }
    __syncthreads();
#pragma unroll
    for (int i = 0; i < 4; i++) {
        int c = c0 + ty + i * 8, cc = ty + i * 8;
        xct[((size_t)b * CIN + c) * T0 + t0 + tx] = tile[tx][cc];
        if (tx < 16) {
            float v = 0.5f * (tile[2 * tx][cc] + tile[2 * tx + 1][cc]);
            s1[((size_t)b * CIN + c) * (T0 / 2) + t0 / 2 + tx] = v;
        }
        if (tx < 8) {
            float v = 0.25f * (tile[4 * tx][cc] + tile[4 * tx + 1][cc]
                             + tile[4 * tx + 2][cc] + tile[4 * tx + 3][cc]);
            s2[((size_t)b * CIN + c) * (T0 / 4) + t0 / 4 + tx] = v;
        }
    }
}

// ---------------- FFT body: 2 real rows per complex FFT, double-stage radix-2 ----------------
#define PHYS(i) ((i) + ((i) >> 5))
template<int LOGT>
__device__ __forceinline__ void fft_body(const float* __restrict__ xm,
        float* __restrict__ part, int pad,
        float* re, float* im, float* twc, float* tws, float* acc) {
    constexpr int T = 1 << LOGT;
    constexpr int F = T / 2;
    int tid = threadIdx.x;
    for (int j = tid; j < F; j += 256) {
        float s, c;
        sincosf(-6.283185307179586f * (float)j / (float)T, &s, &c);
        twc[PHYS(j)] = c; tws[PHYS(j)] = s;
    }
    for (int i = tid; i <= F; i += 256) acc[i] = 0.f;
    __syncthreads();

    int rowbase = blockIdx.x * 8;
    for (int pr = 0; pr < 4; pr++) {
        const float* row0 = xm + (size_t)(rowbase + 2 * pr) * T;
        const float* row1 = row0 + T;
        for (int j = tid; j < T; j += 256) {
            int rv = (int)(__brev((unsigned)j) >> (32 - LOGT));
            re[PHYS(rv)] = row0[j];
            im[PHYS(rv)] = row1[j];
        }
        __syncthreads();
        for (int s = 1; s + 1 <= LOGT; s += 2) {
            int mh = 1 << (s - 1);
            if (tid < T / 4) {
                int k  = tid & (mh - 1);
                int gq = tid >> (s - 1);
                int i0 = (gq << (s + 1)) + k;
                int iA = PHYS(i0), iB = PHYS(i0 + mh);
                int iC = PHYS(i0 + 2 * mh), iD = PHYS(i0 + 3 * mh);
                int t1 = PHYS(k << (LOGT - s));
                int t2 = PHYS(k << (LOGT - s - 1));
                int t3 = PHYS((k + mh) << (LOGT - s - 1));
                float w1r = twc[t1], w1i = tws[t1];
                float w2r = twc[t2], w2i = tws[t2];
                float w3r = twc[t3], w3i = tws[t3];
                float ar = re[iA], ai = im[iA];
                float br = re[iB], bi = im[iB];
                float cr = re[iC], ci = im[iC];
                float dr = re[iD], di = im[iD];
                float tbr = w1r * br - w1i * bi, tbi = w1r * bi + w1i * br;
                float tdr = w1r * dr - w1i * di, tdi = w1r * di + w1i * dr;
                float v0r = ar + tbr, v0i = ai + tbi;
                float v1r = ar - tbr, v1i = ai - tbi;
                float v2r = cr + tdr, v2i = ci + tdi;
                float v3r = cr - tdr, v3i = ci - tdi;
                float t2r = w2r * v2r - w2i * v2i, t2i = w2r * v2i + w2i * v2r;
                float t3r = w3r * v3r - w3i * v3i, t3i = w3r * v3i + w3i * v3r;
                re[iA] = v0r + t2r; im[iA] = v0i + t2i;
                re[iC] = v0r - t2r; im[iC] = v0i - t2i;
                re[iB] = v1r + t3r; im[iB] = v1i + t3i;
                re[iD] = v1r - t3r; im[iD] = v1i - t3i;
            }
            __syncthreads();
        }
        if (LOGT & 1) {
            constexpr int s = LOGT;
            int mh = 1 << (s - 1);
            if (tid < T / 2) {
                int k  = tid & (mh - 1);
                int i1 = PHYS(tid);
                int i2 = PHYS(tid + mh);
                int tw = PHYS(k);
                float wr = twc[tw], wi = tws[tw];
                float xr = re[i2], xi = im[i2];
                float tr = wr * xr - wi * xi;
                float ti = wr * xi + wi * xr;
                float ur = re[i1], ui = im[i1];
                re[i1] = ur + tr; im[i1] = ui + ti;
                re[i2] = ur - tr; im[i2] = ui - ti;
            }
            __syncthreads();
        }
        for (int f = tid; f <= F; f += 256) {
            if (f >= 1) {
                int mf = T - f;
                float rf = re[PHYS(f)], imf = im[PHYS(f)];
                float rm = re[PHYS(mf)], imm = im[PHYS(mf)];
                float m0 = sqrtf((rf + rm) * (rf + rm) + (imf - imm) * (imf - imm));
                float m1 = sqrtf((imf + imm) * (imf + imm) + (rf - rm) * (rf - rm));
                acc[f] += 0.5f * (m0 + m1);
            }
        }
        __syncthreads();
    }
    for (int f = tid; f <= F; f += 256)
        part[(size_t)blockIdx.x * pad + f] = acc[f];
}

__global__ __launch_bounds__(256) void fft_all(const float* __restrict__ xct,
        const float* __restrict__ s1, const float* __restrict__ s2,
        float* __restrict__ parts) {
    __shared__ float re[1056], im[1056], twc[528], tws[528], acc[513];
    int sc = blockIdx.y;
    if (sc == 0)
        fft_body<10>(xct, parts, 520, re, im, twc, tws, acc);
    else if (sc == 1)
        fft_body<9>(s1, parts + (size_t)1024 * 520, 264, re, im, twc, tws, acc);
    else
        fft_body<8>(s2, parts + (size_t)1024 * 520 + (size_t)1024 * 264, 136,
                    re, im, twc, tws, acc);
}

// ---------------- stage A: sum 64 rows per block -> parts2[s][16][520] ----------------
__global__ __launch_bounds__(256) void reduce_partA(const float* __restrict__ parts,
                                                    float* __restrict__ parts2) {
    const int PADs[3] = {520, 264, 136};
    const int Fs[3]   = {513, 257, 129};
    const size_t POFF[3] = {0, (size_t)1024 * 520, (size_t)1024 * 520 + (size_t)1024 * 264};
    int s  = blockIdx.y;
    int rs = blockIdx.z;
    int fl = threadIdx.x & 63;
    int rg = threadIdx.x >> 6;
    int f  = blockIdx.x * 64 + fl;
    bool valid = f < Fs[s];
    const float* base = parts + POFF[s];
    int pad = PADs[s];
    float sum = 0.f;
    if (valid) {
        int r0 = rs * 64 + rg * 16;
#pragma unroll
        for (int i = 0; i < 16; i++) sum += base[(size_t)(r0 + i) * pad + f];
    }
    __shared__ float red[256];
    red[threadIdx.x] = sum;
    __syncthreads();
    if (rg == 0 && valid) {
        float tot = red[fl] + red[fl + 64] + red[fl + 128] + red[fl + 192];
        parts2[(size_t)(s * 16 + rs) * 520 + f] = tot;
    }
}

__device__ inline float sum16(const float* __restrict__ p2, int m, int f) {
    const float* b = p2 + (size_t)m * 16 * 520 + f;
    float s = 0.f;
#pragma unroll
    for (int r = 0; r < 16; r++) s += b[r * 520];
    return s;
}

// ---------------- top-3 + geometry base-tables (odd row strides) ----------------
__device__ inline void ins3(float v, int i, float& b0, int& c0,
                            float& b1, int& c1, float& b2, int& c2) {
    bool g0 = (v > b0) || (v == b0 && i < c0);
    bool g1 = (v > b1) || (v == b1 && i < c1);
    bool g2 = (v > b2) || (v == b2 && i < c2);
    if (g0)      { b2 = b1; c2 = c1; b1 = b0; c1 = c0; b0 = v; c0 = i; }
    else if (g1) { b2 = b1; c2 = c1; b1 = v; c1 = i; }
    else if (g2) { b2 = v; c2 = i; }
}

__global__ __launch_bounds__(256) void meta_topk(const float* __restrict__ parts2,
                          const float* __restrict__ slog,
                          int* __restrict__ freqs, float* __restrict__ wk,
                          float* __restrict__ sw,
                          unsigned* __restrict__ tb32g, unsigned short* __restrict__ tb16g) {
    __shared__ float sv[12];
    __shared__ int   si[12];
    __shared__ int   sfr[3];
    const int Fs[3] = {513, 257, 129};
    const int Ts[3] = {1024, 512, 256};
    int m = blockIdx.x;
    int tid = threadIdx.x, lane = tid & 63, wv = tid >> 6;
    int F = Fs[m];
    float b0 = -1e30f, b1 = -1e30f, b2 = -1e30f;
    int   c0 = 0x7fffffff, c1 = 0x7fffffff, c2 = 0x7fffffff;
    for (int i = tid; i < F; i += 256) {
        float v = (i == 0) ? 0.f : sum16(parts2, m, i) * (1.f / 8192.f);
        ins3(v, i, b0, c0, b1, c1, b2, c2);
    }
#pragma unroll
    for (int d = 1; d < 64; d <<= 1) {
        float o0 = __shfl_xor(b0, d), o1 = __shfl_xor(b1, d), o2 = __shfl_xor(b2, d);
        int   i0 = __shfl_xor(c0, d), i1 = __shfl_xor(c1, d), i2 = __shfl_xor(c2, d);
        ins3(o0, i0, b0, c0, b1, c1, b2, c2);
        ins3(o1, i1, b0, c0, b1, c1, b2, c2);
        ins3(o2, i2, b0, c0, b1, c1, b2, c2);
    }
    if (lane == 0) {
        sv[wv * 3 + 0] = b0; si[wv * 3 + 0] = c0;
        sv[wv * 3 + 1] = b1; si[wv * 3 + 1] = c1;
        sv[wv * 3 + 2] = b2; si[wv * 3 + 2] = c2;
    }
    __syncthreads();
    if (tid == 0) {
        float d0 = sv[0], d1 = sv[1], d2 = sv[2];
        int   e0 = si[0], e1 = si[1], e2 = si[2];
        for (int q = 3; q < 12; q++) ins3(sv[q], si[q], d0, e0, d1, e1, d2, e2);
        int fr[3] = {max(1, e0), max(1, e1), max(1, e2)};
        float av[3];
#pragma unroll
        for (int i = 0; i < 3; i++) av[i] = sum16(parts2, m, fr[i]) * (1.f / 8192.f);
        float mx = fmaxf(av[0], fmaxf(av[1], av[2]));
        float x0 = expf(av[0] - mx), x1 = expf(av[1] - mx), x2 = expf(av[2] - mx);
        float inv = 1.f / (x0 + x1 + x2);
        freqs[m * 3 + 0] = fr[0]; freqs[m * 3 + 1] = fr[1]; freqs[m * 3 + 2] = fr[2];
        wk[m * 3 + 0] = x0 * inv; wk[m * 3 + 1] = x1 * inv; wk[m * 3 + 2] = x2 * inv;
        sfr[0] = fr[0]; sfr[1] = fr[1]; sfr[2] = fr[2];
        if (m == 0) {
            float s0 = slog[0], s1 = slog[1], s2 = slog[2];
            float mx2 = fmaxf(s0, fmaxf(s1, s2));
            float e0b = expf(s0 - mx2), e1b = expf(s1 - mx2), e2b = expf(s2 - mx2);
            float inv2 = 3.f / (e0b + e1b + e2b);
            sw[0] = e0b * inv2; sw[1] = e1b * inv2; sw[2] = e2b * inv2;
        }
    }
    __syncthreads();
    // geometry: absolute xpad base per (k,l); halo layout (rows+2) x S, S odd
    int Tm = Ts[m];
    int p0 = Tm / sfr[0], p1 = Tm / sfr[1], p2v = Tm / sfr[2];
    int S0 = (p0 + 2) | 1, S1 = (p1 + 2) | 1, S2v = (p2v + 2) | 1;
    int r0n = (Tm + p0 - 1) / p0, r1n = (Tm + p1 - 1) / p1;
    int off0 = 0;
    int off1 = (r0n + 2) * S0;
    int off2 = off1 + (r1n + 2) * S1;
    for (int l = tid; l < Tm; l += 256) {
        int ra = l / p0, ca = l - ra * p0;
        int rb = l / p1, cb = l - rb * p1;
        int rc = l / p2v, cc = l - rc * p2v;
        unsigned ba = off0 + (ra + 1) * S0 + ca + 1;
        unsigned bb = off1 + (rb + 1) * S1 + cb + 1;
        unsigned bc = off2 + (rc + 1) * S2v + cc + 1;
        tb32g[m * 1024 + l] = ba | (bb << 16);
        tb16g[m * 1024 + l] = (unsigned short)bc;
    }
}

// ---------------- prep: W2 fold + biases + sw-prescaled w_t->bf16 + row sums ----------------
__global__ __launch_bounds__(256) void prep_all(const float* __restrict__ w_ch,
        const float* __restrict__ pw_w, const float* __restrict__ pw_b,
        const float* __restrict__ wt0, const float* __restrict__ wt1,
        const float* __restrict__ wt2, const float* __restrict__ swb,
        unsigned short* __restrict__ w2ot, float* __restrict__ pbs,
        unsigned short* __restrict__ wtb, float* __restrict__ wsum) {
    int tid = threadIdx.x;
    int bx = blockIdx.x;
    if (bx < 64) {
        int idx = bx * 256 + tid;
        int c = idx >> 7, o = idx & 127;
        float acc = 0.f;
        for (int h = 0; h < HID; h++) acc += w_ch[o * HID + h] * pw_w[h * CIN + c];
        w2ot[o * 128 + (c ^ ((o & 7) << 3))] = f2bf(acc);
        return;
    }
    if (bx == 64) {
        if (tid < 128) {
            float pb = 0.f, s = 0.f;
            for (int h = 0; h < HID; h++) {
                float w = w_ch[tid * HID + h];
                pb += w * pw_b[h]; s += w;
            }
            pbs[tid] = pb; pbs[128 + tid] = s;
        }
        return;
    }
    int wid = (bx - 65) * 4 + (tid >> 6);
    int lane = tid & 63;
    const float* src; int T, p, m; int moff;
    if (wid < 192)      { m = 0; p = wid;       src = wt0; T = 1024; moff = 0; }
    else if (wid < 384) { m = 1; p = wid - 192; src = wt1; T = 512;  moff = 1024; }
    else                { m = 2; p = wid - 384; src = wt2; T = 256;  moff = 1536; }
    float swm = swb[m];
    const float* row = src + (size_t)p * T;
    unsigned short* dst = wtb + (size_t)p * KTOT + moff;
    float s = 0.f;
    for (int j = lane; j < T; j += 64) {
        float v = row[j] * swm; s += v; dst[j] = f2bf(v);
    }
#pragma unroll
    for (int d = 1; d < 64; d <<= 1) s += __shfl_xor(s, d);
    if (lane == 0) wsum[m * 192 + p] = s;
}

// ---------------- depthwise mix: haloed folded grids (odd stride), no masks ----------------
template<int T>
__device__ __forceinline__ void dwmix_body(const float* __restrict__ xm,
        const float* __restrict__ dw_w, const float* __restrict__ dw_b,
        const int* __restrict__ freqs, const float* __restrict__ wkbuf,
        const unsigned* __restrict__ tb32g, const unsigned short* __restrict__ tb16g,
        int m, int moff, unsigned short* __restrict__ dwm, float* xs) {
    constexpr int NP = T / 256;
    int tid = threadIdx.x;
    int c = blockIdx.x, b = blockIdx.y;
    int S0, S1, S2; float wkv[3]; int tot;
    {
        int off = 0; int Sv[3];
#pragma unroll
        for (int k = 0; k < 3; k++) {
            int f = freqs[m * 3 + k];
            int p = T / f;
            int S = (p + 2) | 1;                // odd row stride: bank-spread
            Sv[k] = S;
            int rows = (T + p - 1) / p;
            off += (rows + 2) * S;
            wkv[k] = wkbuf[m * 3 + k];
        }
        S0 = Sv[0]; S1 = Sv[1]; S2 = Sv[2]; tot = off;
    }
    for (int i = tid; i < tot; i += 256) xs[i] = 0.f;
    __syncthreads();
    const float* src = xm + ((size_t)b * CIN + c) * T;
    const unsigned* t32 = tb32g + m * 1024;
    const unsigned short* t16 = tb16g + m * 1024;
    unsigned w32r[NP]; int b2r[NP];
#pragma unroll
    for (int i = 0; i < NP; i++) {
        int l = i * 256 + tid;
        float xv = src[l];
        unsigned w32 = t32[l];
        int b2v = t16[l];
        w32r[i] = w32; b2r[i] = b2v;
        xs[w32 & 0xffff] = xv;
        xs[w32 >> 16]    = xv;
        xs[b2v]          = xv;
    }
    __syncthreads();

    float wk9[27];
#pragma unroll
    for (int k = 0; k < 3; k++)
#pragma unroll
        for (int q = 0; q < 9; q++) wk9[k * 9 + q] = wkv[k] * dw_w[c * 9 + q];
    float bias = dw_b[c];
    unsigned short* outp = dwm + (size_t)(b * CIN + c) * KTOT + moff;

#pragma unroll
    for (int i = 0; i < NP; i++) {
        unsigned w32 = w32r[i];
        const float* q0 = xs + (w32 & 0xffff);
        const float* q1 = xs + (w32 >> 16);
        const float* q2 = xs + b2r[i];
        float a0 = wk9[0] * q0[-S0 - 1] + wk9[1] * q0[-S0] + wk9[2] * q0[-S0 + 1]
                 + wk9[3] * q0[-1]      + wk9[4] * q0[0]   + wk9[5] * q0[1]
                 + wk9[6] * q0[S0 - 1]  + wk9[7] * q0[S0]  + wk9[8] * q0[S0 + 1];
        float a1 = wk9[9]  * q1[-S1 - 1] + wk9[10] * q1[-S1] + wk9[11] * q1[-S1 + 1]
                 + wk9[12] * q1[-1]      + wk9[13] * q1[0]   + wk9[14] * q1[1]
                 + wk9[15] * q1[S1 - 1]  + wk9[16] * q1[S1]  + wk9[17] * q1[S1 + 1];
        float a2 = wk9[18] * q2[-S2 - 1] + wk9[19] * q2[-S2] + wk9[20] * q2[-S2 + 1]
                 + wk9[21] * q2[-1]      + wk9[22] * q2[0]   + wk9[23] * q2[1]
                 + wk9[24] * q2[S2 - 1]  + wk9[25] * q2[S2]  + wk9[26] * q2[S2 + 1];
        outp[i * 256 + tid] = f2bf(bias + a0 + a1 + a2);
    }
}

__global__ __launch_bounds__(256) void dwmix_all(const float* __restrict__ xct,
        const float* __restrict__ s1, const float* __restrict__ s2,
        const float* __restrict__ dw_w, const float* __restrict__ dw_b,
        const int* __restrict__ freqs, const float* __restrict__ wkbuf,
        const unsigned* __restrict__ tb32g, const unsigned short* __restrict__ tb16g,
        unsigned short* __restrict__ dwm) {
    __shared__ float xs[7232];   // worst-case: f={1,2,3} @ T=1024 with odd strides = 7199
    int sc = blockIdx.z;
    if (sc == 0)
        dwmix_body<1024>(xct, dw_w, dw_b, freqs, wkbuf, tb32g, tb16g, 0, 0, dwm, xs);
    else if (sc == 1)
        dwmix_body<512>(s1, dw_w, dw_b, freqs, wkbuf, tb32g, tb16g, 1, 1024, dwm, xs);
    else
        dwmix_body<256>(s2, dw_w, dw_b, freqs, wkbuf, tb32g, tb16g, 2, 1536, dwm, xs);
}

// ---------------- tp GEMM: C[192][8192] = wtb[192][1792] * dwm[8192][1792]^T ----------------
__global__ __launch_bounds__(256) void tp_gemm(const unsigned short* __restrict__ A,
        const unsigned short* __restrict__ B, unsigned short* __restrict__ C) {
    __shared__ __align__(16) unsigned short As[64 * 72];
    __shared__ __align__(16) unsigned short Bs[64 * 72];
    int tid = threadIdx.x;
    int lane = tid & 63, wave = tid >> 6;
    int wm = (wave >> 1) * 32, wn = (wave & 1) * 32;
    int p0 = blockIdx.x * 64, n0 = blockIdx.y * 64;
    f32x4 acc[2][2];
#pragma unroll
    for (int i = 0; i < 2; i++)
#pragma unroll
        for (int j = 0; j < 2; j++) acc[i][j] = (f32x4){0.f, 0.f, 0.f, 0.f};

    int r = tid >> 2, seg = tid & 3;
    const unsigned short* ga = A + (size_t)(p0 + r) * KTOT + seg * 16;
    const unsigned short* gb = B + (size_t)(n0 + r) * KTOT + seg * 16;
    unsigned short* la = &As[r * 72 + seg * 16];
    unsigned short* lb = &Bs[r * 72 + seg * 16];
    int fr = lane & 15, fk = (lane >> 4) * 8;

    for (int k0 = 0; k0 < KTOT; k0 += 64) {
        __syncthreads();
        *(uint4*)la       = *(const uint4*)ga;
        *(uint4*)(la + 8) = *(const uint4*)(ga + 8);
        *(uint4*)lb       = *(const uint4*)gb;
        *(uint4*)(lb + 8) = *(const uint4*)(gb + 8);
        ga += 64; gb += 64;
        __syncthreads();
#pragma unroll
        for (int ks = 0; ks < 2; ks++) {
            int ko = ks * 32 + fk;
            s16x8 a0 = *(const s16x8*)&As[(wm + fr) * 72 + ko];
            s16x8 a1 = *(const s16x8*)&As[(wm + 16 + fr) * 72 + ko];
            s16x8 b0 = *(const s16x8*)&Bs[(wn + fr) * 72 + ko];
            s16x8 b1 = *(const s16x8*)&Bs[(wn + 16 + fr) * 72 + ko];
            acc[0][0] = __builtin_amdgcn_mfma_f32_16x16x32_bf16(a0, b0, acc[0][0], 0, 0, 0);
            acc[0][1] = __builtin_amdgcn_mfma_f32_16x16x32_bf16(a0, b1, acc[0][1], 0, 0, 0);
            acc[1][0] = __builtin_amdgcn_mfma_f32_16x16x32_bf16(a1, b0, acc[1][0], 0, 0, 0);
            acc[1][1] = __builtin_amdgcn_mfma_f32_16x16x32_bf16(a1, b1, acc[1][1], 0, 0, 0);
        }
    }
    int crow = (lane >> 4) * 4, ccol = lane & 15;
#pragma unroll
    for (int i = 0; i < 2; i++)
#pragma unroll
        for (int j = 0; j < 2; j++) {
            int col = n0 + wn + j * 16 + ccol;
#pragma unroll
            for (int reg = 0; reg < 4; reg++) {
                int row = p0 + wm + i * 16 + crow + reg;
                C[(size_t)row * 8192 + col] = f2bf(acc[i][j][reg]);
            }
        }
}

// ---------------- final: out = residual + W2@tps + biases ----------------
__global__ __launch_bounds__(256) void final_out(const float* __restrict__ x,
        const unsigned short* __restrict__ tp, const unsigned short* __restrict__ w2ot,
        const float* __restrict__ pbs, const float* __restrict__ wsum,
        const float* __restrict__ bt0, const float* __restrict__ bt1,
        const float* __restrict__ bt2, const float* __restrict__ b_ch,
        const float* __restrict__ swb, float* __restrict__ out) {
    __shared__ unsigned short w2s[128 * 128];
    __shared__ float tpsS[32][128];
    __shared__ float wsS[32], btS[32];
    int tid = threadIdx.x;
    int r0 = blockIdx.x * 32;
    float sw0 = swb[0], sw1 = swb[1], sw2 = swb[2];

#pragma unroll
    for (int i = 0; i < 8; i++)
        ((uint4*)w2s)[i * 256 + tid] = ((const uint4*)w2ot)[i * 256 + tid];
#pragma unroll
    for (int it = 0; it < 2; it++) {
        int idx = tid + it * 256;
        int rr = idx >> 4, u = idx & 15;
        int r = r0 + rr;
        int b2 = r / 192, p2 = r - b2 * 192;
        size_t base = (size_t)p2 * 8192 + (size_t)b2 * 128 + u * 8;
        uint4 q0 = *(const uint4*)&tp[base];
        const unsigned* a0 = (const unsigned*)&q0;
        float o8[8];
#pragma unroll
        for (int w = 0; w < 4; w++) {
            o8[2 * w]     = bf2f(a0[w] & 0xffff);
            o8[2 * w + 1] = bf2f(a0[w] >> 16);
        }
        *(float4*)&tpsS[rr][u * 8]     = *(float4*)&o8[0];
        *(float4*)&tpsS[rr][u * 8 + 4] = *(float4*)&o8[4];
    }
    if (tid < 32) {
        int r = r0 + tid;
        int b2 = r / 192, p = r - b2 * 192;
        wsS[tid] = wsum[p] + wsum[192 + p] + wsum[384 + p];   // already sw-scaled
        btS[tid] = sw0 * bt0[p] + sw1 * bt1[p] + sw2 * bt2[p];
    }
    __syncthreads();

    int o = tid & 127, half = tid >> 7;
    int rbase = half * 16;
    float pbv  = pbs[o];
    float schv = pbs[128 + o];
    float bchv = (sw0 + sw1 + sw2) * b_ch[o];
    float acc[16];
#pragma unroll
    for (int rr = 0; rr < 16; rr++) acc[rr] = 0.f;

#pragma unroll 2
    for (int cb8 = 0; cb8 < 16; cb8++) {
        uint4 wv = *(const uint4*)&w2s[o * 128 + ((cb8 ^ (o & 7)) << 3)];
        const unsigned* aw = (const unsigned*)&wv;
        float wf[8];
#pragma unroll
        for (int w = 0; w < 4; w++) {
            wf[2 * w]     = bf2f(aw[w] & 0xffff);
            wf[2 * w + 1] = bf2f(aw[w] >> 16);
        }
        int cc = cb8 * 8;
#pragma unroll
        for (int rr = 0; rr < 16; rr++) {
            const float* tr = &tpsS[rbase + rr][cc];
            float4 t0 = *(const float4*)tr;
            float4 t1 = *(const float4*)(tr + 4);
            acc[rr] += wf[0] * t0.x + wf[1] * t0.y + wf[2] * t0.z + wf[3] * t0.w
                     + wf[4] * t1.x + wf[5] * t1.y + wf[6] * t1.z + wf[7] * t1.w;
        }
    }
#pragma unroll
    for (int rr = 0; rr < 16; rr++) {
        int r = r0 + rbase + rr;
        int b2 = r / 192, p = r - b2 * 192;
        float res = x[((size_t)b2 * T0 + (T0 - PRED) + p) * CIN + o];
        out[(size_t)r * TGT + o] = res + acc[rr] + pbv * wsS[rbase + rr]
                                 + schv * btS[rbase + rr] + bchv;
    }
}

extern "C" void kernel_launch(void* const* d_in, const int* in_sizes, int n_in,
                              void* d_out, int out_size, void* d_ws, size_t ws_size,
                              hipStream_t stream) {
    const float* x    = (const float*)d_in[0];
    const float* dw_w = (const float*)d_in[1];
    const float* dw_b = (const float*)d_in[2];
    const float* pw_w = (const float*)d_in[3];
    const float* pw_b = (const float*)d_in[4];
    const float* wt0  = (const float*)d_in[5];
    const float* bt0  = (const float*)d_in[6];
    const float* wt1  = (const float*)d_in[7];
    const float* bt1  = (const float*)d_in[8];
    const float* wt2  = (const float*)d_in[9];
    const float* bt2  = (const float*)d_in[10];
    const float* w_ch = (const float*)d_in[11];
    const float* b_ch = (const float*)d_in[12];
    const float* slog = (const float*)d_in[13];
    float* out = (float*)d_out;
    float* ws  = (float*)d_ws;

    float* xct    = ws + XCT_OFF;
    float* s1b    = ws + S1_OFF;
    float* s2b    = ws + S2_OFF;
    float* parts  = ws + P0_OFF;
    float* parts2 = ws + PARTS2_OFF;
    int*   freqs  = (int*)(ws + META_OFF);
    float* wkb    = ws + META_OFF + 16;
    float* swb    = ws + META_OFF + 32;
    unsigned short* w2tb = (unsigned short*)(ws + W2T_OFF);
    float* pbs    = ws + PBS_OFF;
    float* wsumb  = ws + WSUM_OFF;
    unsigned*       tb32g = (unsigned*)(ws + TB32_OFF);
    unsigned short* tb16g = (unsigned short*)(ws + TB16_OFF);
    unsigned short* wtb  = (unsigned short*)(ws + WTB_OFF);
    unsigned short* dwm  = (unsigned short*)(ws + DWM_OFF);
    unsigned short* tpb  = (unsigned short*)(ws + TP_OFF);

    front<<<dim3(32, 4, NB), dim3(32, 8, 1), 0, stream>>>(x, xct, s1b, s2b);
    fft_all<<<dim3(1024, 3), 256, 0, stream>>>(xct, s1b, s2b, parts);
    reduce_partA<<<dim3(9, 3, 16), 256, 0, stream>>>(parts, parts2);
    meta_topk<<<3, 256, 0, stream>>>(parts2, slog, freqs, wkb, swb, tb32g, tb16g);
    prep_all<<<209, 256, 0, stream>>>(w_ch, pw_w, pw_b, wt0, wt1, wt2, swb,
                                      w2tb, pbs, wtb, wsumb);
    dwmix_all<<<dim3(CIN, NB, 3), 256, 0, stream>>>(xct, s1b, s2b, dw_w, dw_b,
                                                    freqs, wkb, tb32g, tb16g, dwm);
    tp_gemm<<<dim3(3, 128), 256, 0, stream>>>(wtb, dwm, tpb);
    final_out<<<384, 256, 0, stream>>>(x, tpb, w2tb, pbs, wsumb,
                                       bt0, bt1, bt2, b_ch, swb, out);
}

// Round 10
// 193.165 us; speedup vs baseline: 1.0287x; 1.0287x over previous
//
#include <hip/hip_runtime.h>
#include <math.h>

#define NB   64
#define T0   1024
#define CIN  128
#define HID  256
#define TGT  128
#define PRED 192
#define NROWS (NB*CIN)
#define KTOT 1792   // 1024+512+256

typedef __attribute__((ext_vector_type(4))) float f32x4;
typedef __attribute__((ext_vector_type(8))) short s16x8;

// ---------------- workspace layout (float offsets) ----------------
static const size_t XCT_OFF    = 0;          // [64][128][1024] f32
static const size_t S1_OFF     = 8388608;    // [64][128][512]
static const size_t S2_OFF     = 12582912;   // [64][128][256]
static const size_t P0_OFF     = 14680064;   // fft partials [1024][520+264+136]
static const size_t PARTS2_OFF = 15622144;   // [3][16][520]
static const size_t META_OFF   = 15647104;   // freqs int[9]@0, wk f32[9]@16, sw f32[3]@32
static const size_t W2T_OFF    = 15647168;   // [128 o][128 c-swizzled] bf16
static const size_t PBS_OFF    = 15655360;   // Pb[128], S_ch[128]
static const size_t WSUM_OFF   = 15655616;   // [3][192] (sw-prescaled)
static const size_t TB32_OFF   = 15656192;   // u32 [3][1024] base pairs
static const size_t TB16_OFF   = 15659264;   // u16 [3][1024] base k2
static const size_t WTB_OFF    = 15660800;   // bf16 [192][1792] sw-prescaled
static const size_t DWM_OFF    = 15832832;   // bf16 [8192][1792]
static const size_t TP_OFF     = 23172864;   // bf16 [192][8192]
// end = 23959296 floats = 95.8 MB

__device__ inline unsigned short f2bf(float x) {
    union { float f; unsigned u; } v; v.f = x;
    unsigned r = (v.u + 0x7FFFu + ((v.u >> 16) & 1u)) >> 16;
    return (unsigned short)r;
}
__device__ inline float bf2f(unsigned short u) {
    union { unsigned u; float f; } v; v.u = ((unsigned)u) << 16;
    return v.f;
}

// ---------------- fused: transpose x[B,T,C]->xct[B,C,T] + pool1 + pool2 ----------------
__global__ __launch_bounds__(256) void front(const float* __restrict__ x,
        float* __restrict__ xct, float* __restrict__ s1, float* __restrict__ s2) {
    __shared__ float tile[32][33];
    int b = blockIdx.z;
    int t0 = blockIdx.x * 32, c0 = blockIdx.y * 32;
    int tx = threadIdx.x, ty = threadIdx.y;       // 32 x 8
#pragma unroll
    for (int i = 0; i < 4; i++) {
        int t = t0 + ty + i * 8, c = c0 + tx;
        tile[ty + i * 8][tx] = x[((size_t)b * T0 + t) * CIN + c];
    }
    __syncthreads();
#pragma unroll
    for (int i = 0; i < 4; i++) {
        int c = c0 + ty + i * 8, cc = ty + i * 8;
        xct[((size_t)b * CIN + c) * T0 + t0 + tx] = tile[tx][cc];
        if (tx < 16) {
            float v = 0.5f * (tile[2 * tx][cc] + tile[2 * tx + 1][cc]);
            s1[((size_t)b * CIN + c) * (T0 / 2) + t0 / 2 + tx] = v;
        }
        if (tx < 8) {
            float v = 0.25f * (tile[4 * tx][cc] + tile[4 * tx + 1][cc]
                             + tile[4 * tx + 2][cc] + tile[4 * tx + 3][cc]);
            s2[((size_t)b * CIN + c) * (T0 / 4) + t0 / 4 + tx] = v;
        }
    }
}

// ---------------- prep body: W2 fold + biases + sw-prescaled w_t->bf16 + row sums ----------------
__device__ void prep_body(const float* __restrict__ w_ch,
        const float* __restrict__ pw_w, const float* __restrict__ pw_b,
        const float* __restrict__ wt0, const float* __restrict__ wt1,
        const float* __restrict__ wt2, const float* __restrict__ slog,
        unsigned short* __restrict__ w2ot, float* __restrict__ pbs,
        unsigned short* __restrict__ wtb, float* __restrict__ wsum) {
    int tid = threadIdx.x;
    int bx = blockIdx.x;
    if (bx >= 209) return;
    if (bx < 64) {
        int idx = bx * 256 + tid;
        int c = idx >> 7, o = idx & 127;
        float acc = 0.f;
        for (int h = 0; h < HID; h++) acc += w_ch[o * HID + h] * pw_w[h * CIN + c];
        w2ot[o * 128 + (c ^ ((o & 7) << 3))] = f2bf(acc);
        return;
    }
    if (bx == 64) {
        if (tid < 128) {
            float pb = 0.f, s = 0.f;
            for (int h = 0; h < HID; h++) {
                float w = w_ch[tid * HID + h];
                pb += w * pw_b[h]; s += w;
            }
            pbs[tid] = pb; pbs[128 + tid] = s;
        }
        return;
    }
    // sw computed locally (prep runs concurrently with meta_topk)
    float s0l = slog[0], s1l = slog[1], s2l = slog[2];
    float mx = fmaxf(s0l, fmaxf(s1l, s2l));
    float e0 = expf(s0l - mx), e1 = expf(s1l - mx), e2 = expf(s2l - mx);
    float inv = 3.f / (e0 + e1 + e2);
    float swl[3] = {e0 * inv, e1 * inv, e2 * inv};

    int wid = (bx - 65) * 4 + (tid >> 6);
    int lane = tid & 63;
    const float* src; int T, p, m; int moff;
    if (wid < 192)      { m = 0; p = wid;       src = wt0; T = 1024; moff = 0; }
    else if (wid < 384) { m = 1; p = wid - 192; src = wt1; T = 512;  moff = 1024; }
    else                { m = 2; p = wid - 384; src = wt2; T = 256;  moff = 1536; }
    float swm = swl[m];
    const float* row = src + (size_t)p * T;
    unsigned short* dst = wtb + (size_t)p * KTOT + moff;
    float s = 0.f;
    for (int j = lane; j < T; j += 64) {
        float v = row[j] * swm; s += v; dst[j] = f2bf(v);
    }
#pragma unroll
    for (int d = 1; d < 64; d <<= 1) s += __shfl_xor(s, d);
    if (lane == 0) wsum[m * 192 + p] = s;
}

// ---------------- FFT body: reg radix-4 first 2 stages + double-stage radix-2 ----------------
#define PHYS(i) ((i) + ((i) >> 5))
template<int LOGT>
__device__ __forceinline__ void fft_body(const float* __restrict__ xm,
        float* __restrict__ part, int pad,
        float* re, float* im, float* twc, float* tws, float* acc) {
    constexpr int T = 1 << LOGT;
    constexpr int F = T / 2;
    int tid = threadIdx.x;
    for (int j = tid; j < F; j += 256) {
        float s, c;
        sincosf(-6.283185307179586f * (float)j / (float)T, &s, &c);
        twc[PHYS(j)] = c; tws[PHYS(j)] = s;
    }
    for (int i = tid; i <= F; i += 256) acc[i] = 0.f;
    __syncthreads();

    int rowbase = blockIdx.x * 8;
    for (int pr = 0; pr < 4; pr++) {
        const float* row0 = xm + (size_t)(rowbase + 2 * pr) * T;
        const float* row1 = row0 + T;
        // load + stages 1-2 (twiddles 1 and -i) in registers
        if (tid < T / 4) {
            int base = (LOGT > 2) ? (int)(__brev((unsigned)tid) >> (32 - (LOGT - 2))) : 0;
            float x0r = row0[base],             x0i = row1[base];
            float x1r = row0[base + T / 2],     x1i = row1[base + T / 2];
            float x2r = row0[base + T / 4],     x2i = row1[base + T / 4];
            float x3r = row0[base + 3 * T / 4], x3i = row1[base + 3 * T / 4];
            float ar = x0r + x1r, ai = x0i + x1i;
            float br = x0r - x1r, bi = x0i - x1i;
            float cr = x2r + x3r, ci = x2i + x3i;
            float dr = x2r - x3r, di = x2i - x3i;
            int o = 4 * tid;
            re[PHYS(o)]     = ar + cr;  im[PHYS(o)]     = ai + ci;
            re[PHYS(o + 2)] = ar - cr;  im[PHYS(o + 2)] = ai - ci;
            re[PHYS(o + 1)] = br + di;  im[PHYS(o + 1)] = bi - dr;
            re[PHYS(o + 3)] = br - di;  im[PHYS(o + 3)] = bi + dr;
        }
        __syncthreads();
        for (int s = 3; s + 1 <= LOGT; s += 2) {
            int mh = 1 << (s - 1);
            if (tid < T / 4) {
                int k  = tid & (mh - 1);
                int gq = tid >> (s - 1);
                int i0 = (gq << (s + 1)) + k;
                int iA = PHYS(i0), iB = PHYS(i0 + mh);
                int iC = PHYS(i0 + 2 * mh), iD = PHYS(i0 + 3 * mh);
                int t1 = PHYS(k << (LOGT - s));
                int t2 = PHYS(k << (LOGT - s - 1));
                int t3 = PHYS((k + mh) << (LOGT - s - 1));
                float w1r = twc[t1], w1i = tws[t1];
                float w2r = twc[t2], w2i = tws[t2];
                float w3r = twc[t3], w3i = tws[t3];
                float ar = re[iA], ai = im[iA];
                float br = re[iB], bi = im[iB];
                float cr = re[iC], ci = im[iC];
                float dr = re[iD], di = im[iD];
                float tbr = w1r * br - w1i * bi, tbi = w1r * bi + w1i * br;
                float tdr = w1r * dr - w1i * di, tdi = w1r * di + w1i * dr;
                float v0r = ar + tbr, v0i = ai + tbi;
                float v1r = ar - tbr, v1i = ai - tbi;
                float v2r = cr + tdr, v2i = ci + tdi;
                float v3r = cr - tdr, v3i = ci - tdi;
                float t2r = w2r * v2r - w2i * v2i, t2i = w2r * v2i + w2i * v2r;
                float t3r = w3r * v3r - w3i * v3i, t3i = w3r * v3i + w3i * v3r;
                re[iA] = v0r + t2r; im[iA] = v0i + t2i;
                re[iC] = v0r - t2r; im[iC] = v0i - t2i;
                re[iB] = v1r + t3r; im[iB] = v1i + t3i;
                re[iD] = v1r - t3r; im[iD] = v1i - t3i;
            }
            __syncthreads();
        }
        if (LOGT & 1) {                          // leftover single stage s = LOGT
            constexpr int s = LOGT;
            int mh = 1 << (s - 1);
            if (tid < T / 2) {
                int k  = tid & (mh - 1);
                int i1 = PHYS(tid);
                int i2 = PHYS(tid + mh);
                int tw = PHYS(k);
                float wr = twc[tw], wi = tws[tw];
                float xr = re[i2], xi = im[i2];
                float tr = wr * xr - wi * xi;
                float ti = wr * xi + wi * xr;
                float ur = re[i1], ui = im[i1];
                re[i1] = ur + tr; im[i1] = ui + ti;
                re[i2] = ur - tr; im[i2] = ui - ti;
            }
            __syncthreads();
        }
        for (int f = tid; f <= F; f += 256) {
            if (f >= 1) {
                int mf = T - f;
                float rf = re[PHYS(f)], imf = im[PHYS(f)];
                float rm = re[PHYS(mf)], imm = im[PHYS(mf)];
                float m0 = sqrtf((rf + rm) * (rf + rm) + (imf - imm) * (imf - imm));
                float m1 = sqrtf((imf + imm) * (imf + imm) + (rf - rm) * (rf - rm));
                acc[f] += 0.5f * (m0 + m1);
            }
        }
        __syncthreads();
    }
    for (int f = tid; f <= F; f += 256)
        part[(size_t)blockIdx.x * pad + f] = acc[f];
}

__global__ __launch_bounds__(256) void fft_all(const float* __restrict__ xct,
        const float* __restrict__ s1, const float* __restrict__ s2,
        float* __restrict__ parts,
        const float* __restrict__ w_ch, const float* __restrict__ pw_w,
        const float* __restrict__ pw_b, const float* __restrict__ wt0,
        const float* __restrict__ wt1, const float* __restrict__ wt2,
        const float* __restrict__ slog,
        unsigned short* __restrict__ w2ot, float* __restrict__ pbs,
        unsigned short* __restrict__ wtb, float* __restrict__ wsum) {
    __shared__ float re[1056], im[1056], twc[528], tws[528], acc[513];
    int sc = blockIdx.y;
    if (sc == 3) {
        prep_body(w_ch, pw_w, pw_b, wt0, wt1, wt2, slog, w2ot, pbs, wtb, wsum);
        return;
    }
    if (sc == 0)
        fft_body<10>(xct, parts, 520, re, im, twc, tws, acc);
    else if (sc == 1)
        fft_body<9>(s1, parts + (size_t)1024 * 520, 264, re, im, twc, tws, acc);
    else
        fft_body<8>(s2, parts + (size_t)1024 * 520 + (size_t)1024 * 264, 136,
                    re, im, twc, tws, acc);
}

// ---------------- stage A: sum 64 rows per block -> parts2[s][16][520] ----------------
__global__ __launch_bounds__(256) void reduce_partA(const float* __restrict__ parts,
                                                    float* __restrict__ parts2) {
    const int PADs[3] = {520, 264, 136};
    const int Fs[3]   = {513, 257, 129};
    const size_t POFF[3] = {0, (size_t)1024 * 520, (size_t)1024 * 520 + (size_t)1024 * 264};
    int s  = blockIdx.y;
    int rs = blockIdx.z;
    int fl = threadIdx.x & 63;
    int rg = threadIdx.x >> 6;
    int f  = blockIdx.x * 64 + fl;
    bool valid = f < Fs[s];
    const float* base = parts + POFF[s];
    int pad = PADs[s];
    float sum = 0.f;
    if (valid) {
        int r0 = rs * 64 + rg * 16;
#pragma unroll
        for (int i = 0; i < 16; i++) sum += base[(size_t)(r0 + i) * pad + f];
    }
    __shared__ float red[256];
    red[threadIdx.x] = sum;
    __syncthreads();
    if (rg == 0 && valid) {
        float tot = red[fl] + red[fl + 64] + red[fl + 128] + red[fl + 192];
        parts2[(size_t)(s * 16 + rs) * 520 + f] = tot;
    }
}

__device__ inline float sum16(const float* __restrict__ p2, int m, int f) {
    const float* b = p2 + (size_t)m * 16 * 520 + f;
    float s = 0.f;
#pragma unroll
    for (int r = 0; r < 16; r++) s += b[r * 520];
    return s;
}

// ---------------- top-3 + geometry base-tables (odd row strides) ----------------
__device__ inline void ins3(float v, int i, float& b0, int& c0,
                            float& b1, int& c1, float& b2, int& c2) {
    bool g0 = (v > b0) || (v == b0 && i < c0);
    bool g1 = (v > b1) || (v == b1 && i < c1);
    bool g2 = (v > b2) || (v == b2 && i < c2);
    if (g0)      { b2 = b1; c2 = c1; b1 = b0; c1 = c0; b0 = v; c0 = i; }
    else if (g1) { b2 = b1; c2 = c1; b1 = v; c1 = i; }
    else if (g2) { b2 = v; c2 = i; }
}

__global__ __launch_bounds__(256) void meta_topk(const float* __restrict__ parts2,
                          const float* __restrict__ slog,
                          int* __restrict__ freqs, float* __restrict__ wk,
                          float* __restrict__ sw,
                          unsigned* __restrict__ tb32g, unsigned short* __restrict__ tb16g) {
    __shared__ float sv[12];
    __shared__ int   si[12];
    __shared__ int   sfr[3];
    const int Fs[3] = {513, 257, 129};
    const int Ts[3] = {1024, 512, 256};
    int m = blockIdx.x;
    int tid = threadIdx.x, lane = tid & 63, wv = tid >> 6;
    int F = Fs[m];
    float b0 = -1e30f, b1 = -1e30f, b2 = -1e30f;
    int   c0 = 0x7fffffff, c1 = 0x7fffffff, c2 = 0x7fffffff;
    for (int i = tid; i < F; i += 256) {
        float v = (i == 0) ? 0.f : sum16(parts2, m, i) * (1.f / 8192.f);
        ins3(v, i, b0, c0, b1, c1, b2, c2);
    }
#pragma unroll
    for (int d = 1; d < 64; d <<= 1) {
        float o0 = __shfl_xor(b0, d), o1 = __shfl_xor(b1, d), o2 = __shfl_xor(b2, d);
        int   i0 = __shfl_xor(c0, d), i1 = __shfl_xor(c1, d), i2 = __shfl_xor(c2, d);
        ins3(o0, i0, b0, c0, b1, c1, b2, c2);
        ins3(o1, i1, b0, c0, b1, c1, b2, c2);
        ins3(o2, i2, b0, c0, b1, c1, b2, c2);
    }
    if (lane == 0) {
        sv[wv * 3 + 0] = b0; si[wv * 3 + 0] = c0;
        sv[wv * 3 + 1] = b1; si[wv * 3 + 1] = c1;
        sv[wv * 3 + 2] = b2; si[wv * 3 + 2] = c2;
    }
    __syncthreads();
    if (tid == 0) {
        float d0 = sv[0], d1 = sv[1], d2 = sv[2];
        int   e0 = si[0], e1 = si[1], e2 = si[2];
        for (int q = 3; q < 12; q++) ins3(sv[q], si[q], d0, e0, d1, e1, d2, e2);
        int fr[3] = {max(1, e0), max(1, e1), max(1, e2)};
        float av[3];
#pragma unroll
        for (int i = 0; i < 3; i++) av[i] = sum16(parts2, m, fr[i]) * (1.f / 8192.f);
        float mx = fmaxf(av[0], fmaxf(av[1], av[2]));
        float x0 = expf(av[0] - mx), x1 = expf(av[1] - mx), x2 = expf(av[2] - mx);
        float inv = 1.f / (x0 + x1 + x2);
        freqs[m * 3 + 0] = fr[0]; freqs[m * 3 + 1] = fr[1]; freqs[m * 3 + 2] = fr[2];
        wk[m * 3 + 0] = x0 * inv; wk[m * 3 + 1] = x1 * inv; wk[m * 3 + 2] = x2 * inv;
        sfr[0] = fr[0]; sfr[1] = fr[1]; sfr[2] = fr[2];
        if (m == 0) {
            float s0 = slog[0], s1 = slog[1], s2 = slog[2];
            float mx2 = fmaxf(s0, fmaxf(s1, s2));
            float e0b = expf(s0 - mx2), e1b = expf(s1 - mx2), e2b = expf(s2 - mx2);
            float inv2 = 3.f / (e0b + e1b + e2b);
            sw[0] = e0b * inv2; sw[1] = e1b * inv2; sw[2] = e2b * inv2;
        }
    }
    __syncthreads();
    // geometry: absolute xpad base per (k,l); halo layout (rows+2) x S, S odd
    int Tm = Ts[m];
    int p0 = Tm / sfr[0], p1 = Tm / sfr[1], p2v = Tm / sfr[2];
    int S0 = (p0 + 2) | 1, S1 = (p1 + 2) | 1, S2v = (p2v + 2) | 1;
    int r0n = (Tm + p0 - 1) / p0, r1n = (Tm + p1 - 1) / p1;
    int off0 = 0;
    int off1 = (r0n + 2) * S0;
    int off2 = off1 + (r1n + 2) * S1;
    for (int l = tid; l < Tm; l += 256) {
        int ra = l / p0, ca = l - ra * p0;
        int rb = l / p1, cb = l - rb * p1;
        int rc = l / p2v, cc = l - rc * p2v;
        unsigned ba = off0 + (ra + 1) * S0 + ca + 1;
        unsigned bb = off1 + (rb + 1) * S1 + cb + 1;
        unsigned bc = off2 + (rc + 1) * S2v + cc + 1;
        tb32g[m * 1024 + l] = ba | (bb << 16);
        tb16g[m * 1024 + l] = (unsigned short)bc;
    }
}

// ---------------- depthwise mix: haloed folded grids (odd stride), no masks ----------------
template<int T>
__device__ __forceinline__ void dwmix_body(const float* __restrict__ xm,
        const float* __restrict__ dw_w, const float* __restrict__ dw_b,
        const int* __restrict__ freqs, const float* __restrict__ wkbuf,
        const unsigned* __restrict__ tb32g, const unsigned short* __restrict__ tb16g,
        int m, int moff, unsigned short* __restrict__ dwm, float* xs) {
    constexpr int NP = T / 256;
    int tid = threadIdx.x;
    int c = blockIdx.x, b = blockIdx.y;
    int S0, S1, S2; float wkv[3]; int tot;
    {
        int off = 0; int Sv[3];
#pragma unroll
        for (int k = 0; k < 3; k++) {
            int f = freqs[m * 3 + k];
            int p = T / f;
            int S = (p + 2) | 1;                // odd row stride
            Sv[k] = S;
            int rows = (T + p - 1) / p;
            off += (rows + 2) * S;
            wkv[k] = wkbuf[m * 3 + k];
        }
        S0 = Sv[0]; S1 = Sv[1]; S2 = Sv[2]; tot = off;
    }
    for (int i = tid; i < tot; i += 256) xs[i] = 0.f;
    __syncthreads();
    const float* src = xm + ((size_t)b * CIN + c) * T;
    const unsigned* t32 = tb32g + m * 1024;
    const unsigned short* t16 = tb16g + m * 1024;
    unsigned w32r[NP]; int b2r[NP];
#pragma unroll
    for (int i = 0; i < NP; i++) {
        int l = i * 256 + tid;
        float xv = src[l];
        unsigned w32 = t32[l];
        int b2v = t16[l];
        w32r[i] = w32; b2r[i] = b2v;
        xs[w32 & 0xffff] = xv;
        xs[w32 >> 16]    = xv;
        xs[b2v]          = xv;
    }
    __syncthreads();

    float wk9[27];
#pragma unroll
    for (int k = 0; k < 3; k++)
#pragma unroll
        for (int q = 0; q < 9; q++) wk9[k * 9 + q] = wkv[k] * dw_w[c * 9 + q];
    float bias = dw_b[c];
    unsigned short* outp = dwm + (size_t)(b * CIN + c) * KTOT + moff;

#pragma unroll
    for (int i = 0; i < NP; i++) {
        unsigned w32 = w32r[i];
        const float* q0 = xs + (w32 & 0xffff);
        const float* q1 = xs + (w32 >> 16);
        const float* q2 = xs + b2r[i];
        float a0 = wk9[0] * q0[-S0 - 1] + wk9[1] * q0[-S0] + wk9[2] * q0[-S0 + 1]
                 + wk9[3] * q0[-1]      + wk9[4] * q0[0]   + wk9[5] * q0[1]
                 + wk9[6] * q0[S0 - 1]  + wk9[7] * q0[S0]  + wk9[8] * q0[S0 + 1];
        float a1 = wk9[9]  * q1[-S1 - 1] + wk9[10] * q1[-S1] + wk9[11] * q1[-S1 + 1]
                 + wk9[12] * q1[-1]      + wk9[13] * q1[0]   + wk9[14] * q1[1]
                 + wk9[15] * q1[S1 - 1]  + wk9[16] * q1[S1]  + wk9[17] * q1[S1 + 1];
        float a2 = wk9[18] * q2[-S2 - 1] + wk9[19] * q2[-S2] + wk9[20] * q2[-S2 + 1]
                 + wk9[21] * q2[-1]      + wk9[22] * q2[0]   + wk9[23] * q2[1]
                 + wk9[24] * q2[S2 - 1]  + wk9[25] * q2[S2]  + wk9[26] * q2[S2 + 1];
        outp[i * 256 + tid] = f2bf(bias + a0 + a1 + a2);
    }
}

// scale 0 alone: worst-case 29 KB LDS
__global__ __launch_bounds__(256) void dwmix_s0(const float* __restrict__ xct,
        const float* __restrict__ dw_w, const float* __restrict__ dw_b,
        const int* __restrict__ freqs, const float* __restrict__ wkbuf,
        const unsigned* __restrict__ tb32g, const unsigned short* __restrict__ tb16g,
        unsigned short* __restrict__ dwm) {
    __shared__ float xs[7232];
    dwmix_body<1024>(xct, dw_w, dw_b, freqs, wkbuf, tb32g, tb16g, 0, 0, dwm, xs);
}

// scales 1+2 merged: 14.6 KB LDS -> 8 blocks/CU (100% occupancy)
__global__ __launch_bounds__(256) void dwmix_s12(const float* __restrict__ s1,
        const float* __restrict__ s2,
        const float* __restrict__ dw_w, const float* __restrict__ dw_b,
        const int* __restrict__ freqs, const float* __restrict__ wkbuf,
        const unsigned* __restrict__ tb32g, const unsigned short* __restrict__ tb16g,
        unsigned short* __restrict__ dwm) {
    __shared__ float xs[3648];
    if (blockIdx.z == 0)
        dwmix_body<512>(s1, dw_w, dw_b, freqs, wkbuf, tb32g, tb16g, 1, 1024, dwm, xs);
    else
        dwmix_body<256>(s2, dw_w, dw_b, freqs, wkbuf, tb32g, tb16g, 2, 1536, dwm, xs);
}

// ---------------- tp GEMM: C[192][8192] = wtb[192][1792] * dwm[8192][1792]^T ----------------
__global__ __launch_bounds__(256) void tp_gemm(const unsigned short* __restrict__ A,
        const unsigned short* __restrict__ B, unsigned short* __restrict__ C) {
    __shared__ __align__(16) unsigned short As[64 * 72];
    __shared__ __align__(16) unsigned short Bs[64 * 72];
    int tid = threadIdx.x;
    int lane = tid & 63, wave = tid >> 6;
    int wm = (wave >> 1) * 32, wn = (wave & 1) * 32;
    int p0 = blockIdx.x * 64, n0 = blockIdx.y * 64;
    f32x4 acc[2][2];
#pragma unroll
    for (int i = 0; i < 2; i++)
#pragma unroll
        for (int j = 0; j < 2; j++) acc[i][j] = (f32x4){0.f, 0.f, 0.f, 0.f};

    int r = tid >> 2, seg = tid & 3;
    const unsigned short* ga = A + (size_t)(p0 + r) * KTOT + seg * 16;
    const unsigned short* gb = B + (size_t)(n0 + r) * KTOT + seg * 16;
    unsigned short* la = &As[r * 72 + seg * 16];
    unsigned short* lb = &Bs[r * 72 + seg * 16];
    int fr = lane & 15, fk = (lane >> 4) * 8;

    for (int k0 = 0; k0 < KTOT; k0 += 64) {
        __syncthreads();
        *(uint4*)la       = *(const uint4*)ga;
        *(uint4*)(la + 8) = *(const uint4*)(ga + 8);
        *(uint4*)lb       = *(const uint4*)gb;
        *(uint4*)(lb + 8) = *(const uint4*)(gb + 8);
        ga += 64; gb += 64;
        __syncthreads();
#pragma unroll
        for (int ks = 0; ks < 2; ks++) {
            int ko = ks * 32 + fk;
            s16x8 a0 = *(const s16x8*)&As[(wm + fr) * 72 + ko];
            s16x8 a1 = *(const s16x8*)&As[(wm + 16 + fr) * 72 + ko];
            s16x8 b0 = *(const s16x8*)&Bs[(wn + fr) * 72 + ko];
            s16x8 b1 = *(const s16x8*)&Bs[(wn + 16 + fr) * 72 + ko];
            acc[0][0] = __builtin_amdgcn_mfma_f32_16x16x32_bf16(a0, b0, acc[0][0], 0, 0, 0);
            acc[0][1] = __builtin_amdgcn_mfma_f32_16x16x32_bf16(a0, b1, acc[0][1], 0, 0, 0);
            acc[1][0] = __builtin_amdgcn_mfma_f32_16x16x32_bf16(a1, b0, acc[1][0], 0, 0, 0);
            acc[1][1] = __builtin_amdgcn_mfma_f32_16x16x32_bf16(a1, b1, acc[1][1], 0, 0, 0);
        }
    }
    int crow = (lane >> 4) * 4, ccol = lane & 15;
#pragma unroll
    for (int i = 0; i < 2; i++)
#pragma unroll
        for (int j = 0; j < 2; j++) {
            int col = n0 + wn + j * 16 + ccol;
#pragma unroll
            for (int reg = 0; reg < 4; reg++) {
                int row = p0 + wm + i * 16 + crow + reg;
                C[(size_t)row * 8192 + col] = f2bf(acc[i][j][reg]);
            }
        }
}

// ---------------- final: out = residual + W2@tps + biases ----------------
__global__ __launch_bounds__(256) void final_out(const float* __restrict__ x,
        const unsigned short* __restrict__ tp, const unsigned short* __restrict__ w2ot,
        const float* __restrict__ pbs, const float* __restrict__ wsum,
        const float* __restrict__ bt0, const float* __restrict__ bt1,
        const float* __restrict__ bt2, const float* __restrict__ b_ch,
        const float* __restrict__ swb, float* __restrict__ out) {
    __shared__ unsigned short w2s[128 * 128];
    __shared__ float tpsS[32][128];
    __shared__ float wsS[32], btS[32];
    int tid = threadIdx.x;
    int r0 = blockIdx.x * 32;
    float sw0 = swb[0], sw1 = swb[1], sw2 = swb[2];

#pragma unroll
    for (int i = 0; i < 8; i++)
        ((uint4*)w2s)[i * 256 + tid] = ((const uint4*)w2ot)[i * 256 + tid];
#pragma unroll
    for (int it = 0; it < 2; it++) {
        int idx = tid + it * 256;
        int rr = idx >> 4, u = idx & 15;
        int r = r0 + rr;
        int b2 = r / 192, p2 = r - b2 * 192;
        size_t base = (size_t)p2 * 8192 + (size_t)b2 * 128 + u * 8;
        uint4 q0 = *(const uint4*)&tp[base];
        const unsigned* a0 = (const unsigned*)&q0;
        float o8[8];
#pragma unroll
        for (int w = 0; w < 4; w++) {
            o8[2 * w]     = bf2f(a0[w] & 0xffff);
            o8[2 * w + 1] = bf2f(a0[w] >> 16);
        }
        *(float4*)&tpsS[rr][u * 8]     = *(float4*)&o8[0];
        *(float4*)&tpsS[rr][u * 8 + 4] = *(float4*)&o8[4];
    }
    if (tid < 32) {
        int r = r0 + tid;
        int b2 = r / 192, p = r - b2 * 192;
        wsS[tid] = wsum[p] + wsum[192 + p] + wsum[384 + p];   // already sw-scaled
        btS[tid] = sw0 * bt0[p] + sw1 * bt1[p] + sw2 * bt2[p];
    }
    __syncthreads();

    int o = tid & 127, half = tid >> 7;
    int rbase = half * 16;
    float pbv  = pbs[o];
    float schv = pbs[128 + o];
    float bchv = (sw0 + sw1 + sw2) * b_ch[o];
    float acc[16];
#pragma unroll
    for (int rr = 0; rr < 16; rr++) acc[rr] = 0.f;

#pragma unroll 2
    for (int cb8 = 0; cb8 < 16; cb8++) {
        uint4 wv = *(const uint4*)&w2s[o * 128 + ((cb8 ^ (o & 7)) << 3)];
        const unsigned* aw = (const unsigned*)&wv;
        float wf[8];
#pragma unroll
        for (int w = 0; w < 4; w++) {
            wf[2 * w]     = bf2f(aw[w] & 0xffff);
            wf[2 * w + 1] = bf2f(aw[w] >> 16);
        }
        int cc = cb8 * 8;
#pragma unroll
        for (int rr = 0; rr < 16; rr++) {
            const float* tr = &tpsS[rbase + rr][cc];
            float4 t0 = *(const float4*)tr;
            float4 t1 = *(const float4*)(tr + 4);
            acc[rr] += wf[0] * t0.x + wf[1] * t0.y + wf[2] * t0.z + wf[3] * t0.w
                     + wf[4] * t1.x + wf[5] * t1.y + wf[6] * t1.z + wf[7] * t1.w;
        }
    }
#pragma unroll
    for (int rr = 0; rr < 16; rr++) {
        int r = r0 + rbase + rr;
        int b2 = r / 192, p = r - b2 * 192;
        float res = x[((size_t)b2 * T0 + (T0 - PRED) + p) * CIN + o];
        out[(size_t)r * TGT + o] = res + acc[rr] + pbv * wsS[rbase + rr]
                                 + schv * btS[rbase + rr] + bchv;
    }
}

extern "C" void kernel_launch(void* const* d_in, const int* in_sizes, int n_in,
                              void* d_out, int out_size, void* d_ws, size_t ws_size,
                              hipStream_t stream) {
    const float* x    = (const float*)d_in[0];
    const float* dw_w = (const float*)d_in[1];
    const float* dw_b = (const float*)d_in[2];
    const float* pw_w = (const float*)d_in[3];
    const float* pw_b = (const float*)d_in[4];
    const float* wt0  = (const float*)d_in[5];
    const float* bt0  = (const float*)d_in[6];
    const float* wt1  = (const float*)d_in[7];
    const float* bt1  = (const float*)d_in[8];
    const float* wt2  = (const float*)d_in[9];
    const float* bt2  = (const float*)d_in[10];
    const float* w_ch = (const float*)d_in[11];
    const float* b_ch = (const float*)d_in[12];
    const float* slog = (const float*)d_in[13];
    float* out = (float*)d_out;
    float* ws  = (float*)d_ws;

    float* xct    = ws + XCT_OFF;
    float* s1b    = ws + S1_OFF;
    float* s2b    = ws + S2_OFF;
    float* parts  = ws + P0_OFF;
    float* parts2 = ws + PARTS2_OFF;
    int*   freqs  = (int*)(ws + META_OFF);
    float* wkb    = ws + META_OFF + 16;
    float* swb    = ws + META_OFF + 32;
    unsigned short* w2tb = (unsigned short*)(ws + W2T_OFF);
    float* pbs    = ws + PBS_OFF;
    float* wsumb  = ws + WSUM_OFF;
    unsigned*       tb32g = (unsigned*)(ws + TB32_OFF);
    unsigned short* tb16g = (unsigned short*)(ws + TB16_OFF);
    unsigned short* wtb  = (unsigned short*)(ws + WTB_OFF);
    unsigned short* dwm  = (unsigned short*)(ws + DWM_OFF);
    unsigned short* tpb  = (unsigned short*)(ws + TP_OFF);

    front<<<dim3(32, 4, NB), dim3(32, 8, 1), 0, stream>>>(x, xct, s1b, s2b);
    fft_all<<<dim3(1024, 4), 256, 0, stream>>>(xct, s1b, s2b, parts,
                                               w_ch, pw_w, pw_b, wt0, wt1, wt2, slog,
                                               w2tb, pbs, wtb, wsumb);
    reduce_partA<<<dim3(9, 3, 16), 256, 0, stream>>>(parts, parts2);
    meta_topk<<<3, 256, 0, stream>>>(parts2, slog, freqs, wkb, swb, tb32g, tb16g);
    dwmix_s0<<<dim3(CIN, NB), 256, 0, stream>>>(xct, dw_w, dw_b, freqs, wkb,
                                                tb32g, tb16g, dwm);
    dwmix_s12<<<dim3(CIN, NB, 2), 256, 0, stream>>>(s1b, s2b, dw_w, dw_b, freqs, wkb,
                                                    tb32g, tb16g, dwm);
    tp_gemm<<<dim3(3, 128), 256, 0, stream>>>(wtb, dwm, tpb);
    final_out<<<384, 256, 0, stream>>>(x, tpb, w2tb, pbs, wsumb,
                                       bt0, bt1, bt2, b_ch, swb, out);
}